// Round 1
// baseline (205.570 us; speedup 1.0000x reference)
//
#include <hip/hip_runtime.h>
#include <stdint.h>

// Problem constants
#define BATCH 16
#define WIDTH 1024
#define NPIX (1024*1024)      // elements per batch row
#define NBINS 2048            // score histogram bins
#define NTASK (BATCH*3)       // 48 (batch x {uncertainty, p, 1-p})
#define CAP 4096              // candidate buffer per task (power of 2 for bitonic)
#define BPB 64                // blocks per batch row for streaming passes
#define CHUNK (NPIX/BPB)      // 16384 elements per block

__device__ __forceinline__ int score_bin(float s) {
    int b = (int)(s * (float)NBINS);
    if (b < 0) b = 0;
    if (b > NBINS - 1) b = NBINS - 1;
    return b;
}

__global__ void zero_ws_kernel(uint32_t* __restrict__ hist, uint32_t* __restrict__ candCount) {
    int i = blockIdx.x * blockDim.x + threadIdx.x;
    if (i < BATCH * 3 * NBINS) hist[i] = 0u;
    if (i < NTASK) candCount[i] = 0u;
}

// Pass 1: per-batch histograms of the three scores.
__global__ __launch_bounds__(256) void hist_kernel(const float* __restrict__ p,
                                                   uint32_t* __restrict__ hist) {
    __shared__ uint32_t lh[3 * NBINS];
    for (int i = threadIdx.x; i < 3 * NBINS; i += 256) lh[i] = 0u;
    __syncthreads();

    int b = blockIdx.x / BPB;
    int chunk = blockIdx.x % BPB;
    const float4* src = (const float4*)(p + (size_t)b * NPIX + (size_t)chunk * CHUNK);

    #pragma unroll 4
    for (int i = 0; i < CHUNK / (256 * 4); ++i) {
        float4 v = src[i * 256 + threadIdx.x];
        float vv[4] = {v.x, v.y, v.z, v.w};
        #pragma unroll
        for (int j = 0; j < 4; ++j) {
            float pv = vv[j];
            float s0 = 1.0f - fabsf(2.0f * pv - 1.0f);   // uncertainty
            atomicAdd(&lh[score_bin(s0)], 1u);
            atomicAdd(&lh[NBINS + score_bin(pv)], 1u);
            atomicAdd(&lh[2 * NBINS + score_bin(1.0f - pv)], 1u);
        }
    }
    __syncthreads();

    uint32_t* gh = hist + (size_t)b * 3 * NBINS;
    for (int i = threadIdx.x; i < 3 * NBINS; i += 256) {
        uint32_t c = lh[i];
        if (c) atomicAdd(&gh[i], c);
    }
}

// Find per-task threshold bin t: count(bins > t) < k <= count(bins >= t)
__global__ void scan_kernel(const uint32_t* __restrict__ hist, uint32_t* __restrict__ thrbin) {
    __shared__ uint32_t h[NBINS];
    int task = blockIdx.x;                       // = b*3 + s
    const uint32_t* gh = hist + (size_t)task * NBINS;
    for (int i = threadIdx.x; i < NBINS; i += blockDim.x) h[i] = gh[i];
    __syncthreads();
    if (threadIdx.x == 0) {
        int k = (task % 3 == 0) ? 512 : 128;
        uint32_t cum = 0; int t = 0;
        for (int bin = NBINS - 1; bin >= 0; --bin) {
            cum += h[bin];
            if ((int)cum >= k) { t = bin; break; }
        }
        thrbin[task] = (uint32_t)t;
    }
}

// Pass 2: collect candidate keys (score_bits << 32 | ~idx) for bins >= threshold.
__global__ __launch_bounds__(256) void collect_kernel(const float* __restrict__ p,
                                                      const uint32_t* __restrict__ thrbin,
                                                      uint32_t* __restrict__ candCount,
                                                      uint64_t* __restrict__ cand) {
    int b = blockIdx.x / BPB;
    int chunk = blockIdx.x % BPB;
    int t0 = (int)thrbin[b * 3 + 0];
    int t1 = (int)thrbin[b * 3 + 1];
    int t2 = (int)thrbin[b * 3 + 2];
    const float4* src = (const float4*)(p + (size_t)b * NPIX + (size_t)chunk * CHUNK);
    int baseIdx = chunk * CHUNK;

    #pragma unroll 4
    for (int i = 0; i < CHUNK / (256 * 4); ++i) {
        float4 v = src[i * 256 + threadIdx.x];
        int eb = baseIdx + (i * 256 + threadIdx.x) * 4;
        float vv[4] = {v.x, v.y, v.z, v.w};
        #pragma unroll
        for (int j = 0; j < 4; ++j) {
            float pv = vv[j];
            uint32_t idx = (uint32_t)(eb + j);
            float s0 = 1.0f - fabsf(2.0f * pv - 1.0f);
            float s2 = 1.0f - pv;
            if (score_bin(s0) >= t0) {
                int task = b * 3 + 0;
                uint32_t pos = atomicAdd(&candCount[task], 1u);
                if (pos < CAP)
                    cand[(size_t)task * CAP + pos] =
                        ((uint64_t)__float_as_uint(s0) << 32) | (uint32_t)(~idx);
            }
            if (score_bin(pv) >= t1) {
                int task = b * 3 + 1;
                uint32_t pos = atomicAdd(&candCount[task], 1u);
                if (pos < CAP)
                    cand[(size_t)task * CAP + pos] =
                        ((uint64_t)__float_as_uint(pv) << 32) | (uint32_t)(~idx);
            }
            if (score_bin(s2) >= t2) {
                int task = b * 3 + 2;
                uint32_t pos = atomicAdd(&candCount[task], 1u);
                if (pos < CAP)
                    cand[(size_t)task * CAP + pos] =
                        ((uint64_t)__float_as_uint(s2) << 32) | (uint32_t)(~idx);
            }
        }
    }
}

// Per-task: bitonic sort candidates descending (key = score bits, tie -> smaller idx),
// emit (x, y) float coords for the top-k.
__global__ __launch_bounds__(1024) void sort_out_kernel(const uint32_t* __restrict__ candCount,
                                                        const uint64_t* __restrict__ cand,
                                                        float* __restrict__ out) {
    __shared__ uint64_t keys[CAP];
    int task = blockIdx.x;
    int b = task / 3, s = task % 3;
    uint32_t nc = candCount[task];
    int n = (nc < CAP) ? (int)nc : CAP;
    for (int i = threadIdx.x; i < CAP; i += 1024)
        keys[i] = (i < n) ? cand[(size_t)task * CAP + i] : 0ull;
    __syncthreads();

    // Bitonic sort, descending
    for (int k2 = 2; k2 <= CAP; k2 <<= 1) {
        for (int j = k2 >> 1; j > 0; j >>= 1) {
            for (int i = threadIdx.x; i < CAP; i += 1024) {
                int ixj = i ^ j;
                if (ixj > i) {
                    uint64_t a = keys[i], c = keys[ixj];
                    bool desc = ((i & k2) == 0);
                    if (desc ? (a < c) : (a > c)) { keys[i] = c; keys[ixj] = a; }
                }
            }
            __syncthreads();
        }
    }

    int k = (s == 0) ? 512 : 128;
    float* dst = (s == 0) ? out + (size_t)b * 512 * 2
               : (s == 1) ? out + 16384 + (size_t)b * 128 * 2
                          : out + 20480 + (size_t)b * 128 * 2;
    for (int r = threadIdx.x; r < k; r += 1024) {
        uint64_t key = keys[r];
        uint32_t idx = ~(uint32_t)key;
        dst[r * 2 + 0] = (float)(idx & (WIDTH - 1));  // x
        dst[r * 2 + 1] = (float)(idx >> 10);          // y
    }
}

extern "C" void kernel_launch(void* const* d_in, const int* in_sizes, int n_in,
                              void* d_out, int out_size, void* d_ws, size_t ws_size,
                              hipStream_t stream) {
    const float* p = (const float*)d_in[0];   // (16,1,1024,1024) fp32; feature_map (d_in[1]) unused
    float* out = (float*)d_out;               // 16*512*2 + 16*128*2 + 16*128*2 = 24576 floats

    // Workspace layout (~2 MB):
    uint64_t* cand = (uint64_t*)d_ws;                         // NTASK*CAP u64
    uint32_t* hist = (uint32_t*)(cand + (size_t)NTASK * CAP); // BATCH*3*NBINS u32
    uint32_t* thrbin = hist + (size_t)BATCH * 3 * NBINS;      // NTASK u32
    uint32_t* candCount = thrbin + NTASK;                     // NTASK u32

    zero_ws_kernel<<<(BATCH * 3 * NBINS + 255) / 256, 256, 0, stream>>>(hist, candCount);
    hist_kernel<<<BATCH * BPB, 256, 0, stream>>>(p, hist);
    scan_kernel<<<NTASK, 256, 0, stream>>>(hist, thrbin);
    collect_kernel<<<BATCH * BPB, 256, 0, stream>>>(p, thrbin, candCount, cand);
    sort_out_kernel<<<NTASK, 1024, 0, stream>>>(candCount, cand, out);
}